// Round 11
// baseline (456.215 us; speedup 1.0000x reference)
//
#include <hip/hip_runtime.h>

#define H 1024
#define MMEM 4096
#define NTOK 8192
#define KTOP 64
#define FTHRESH 0.5f

typedef _Float16 half8 __attribute__((ext_vector_type(8)));  // 8 f16 in 4 VGPRs
typedef float vf4 __attribute__((ext_vector_type(4)));       // MFMA f32 acc

__device__ __forceinline__ short f2h(float x){
  union { _Float16 h; short s; } u; u.h = (_Float16)x; return u.s;
}
__device__ __forceinline__ float h2f(short s){
  union { _Float16 h; short s; } u; u.s = s; return (float)u.h;
}
// order-preserving float->uint32 key (monotone increasing)
__device__ __forceinline__ unsigned fkey_of(float x){
  unsigned u = __float_as_uint(x);
  return (u & 0x80000000u) ? ~u : (u | 0x80000000u);
}
__device__ __forceinline__ float val_of(unsigned k){
  unsigned u = (k & 0x80000000u) ? (k & 0x7fffffffu) : ~k;
  return __uint_as_float(u);
}

// async global->LDS, 16B/lane; LDS dest is wave-uniform base + lane*16 (HW rule)
__device__ __forceinline__ void gload_lds16(const short* g, short* l){
  __builtin_amdgcn_global_load_lds(
      (const __attribute__((address_space(1))) unsigned int*)g,
      (__attribute__((address_space(3))) unsigned int*)l, 16, 0, 0);
}

// ---------------- fused LN+surprise AND prep (independent work, 1 launch) ----------------
__global__ __launch_bounds__(256) void ln_prep_kernel(
    const float* __restrict__ hs, const float* __restrict__ g, const float* __restrict__ be,
    const float* __restrict__ mem, const float* __restrict__ Wq, const float* __restrict__ Wo,
    const float* __restrict__ bq,
    short* __restrict__ n16, float* __restrict__ surprise,
    short* __restrict__ m16, short* __restrict__ wqT, short* __restrict__ wo16,
    float* __restrict__ biasM)
{
  int b = blockIdx.x, tid = threadIdx.x;
  if (b < NTOK){
    int row = b;
    long base = (long)row * H;
    float4 x = ((const float4*)(hs + base))[tid];
    float s1 = x.x + x.y + x.z + x.w;
    float s2 = x.x*x.x + x.y*x.y + x.z*x.z + x.w*x.w;
    __shared__ float r1[4], r2[4], r3[4];
    int w = tid >> 6, lane = tid & 63;
    for (int o = 32; o; o >>= 1){ s1 += __shfl_down(s1, o); s2 += __shfl_down(s2, o); }
    if (lane == 0){ r1[w] = s1; r2[w] = s2; }
    __syncthreads();
    float S1 = r1[0]+r1[1]+r1[2]+r1[3];
    float S2 = r2[0]+r2[1]+r2[2]+r2[3];
    float mean = S1 * (1.0f/H);
    float var  = S2 * (1.0f/H) - mean*mean;
    float rinv = rsqrtf(var + 1e-12f);
    float4 gg = ((const float4*)g)[tid];
    float4 bb = ((const float4*)be)[tid];
    float4 n;
    n.x = (x.x-mean)*rinv*gg.x + bb.x;
    n.y = (x.y-mean)*rinv*gg.y + bb.y;
    n.z = (x.z-mean)*rinv*gg.z + bb.z;
    n.w = (x.w-mean)*rinv*gg.w + bb.w;
    float sa = fabsf(n.x)+fabsf(n.y)+fabsf(n.z)+fabsf(n.w);
    for (int o = 32; o; o >>= 1) sa += __shfl_down(sa, o);
    if (lane == 0) r3[w] = sa;
    __syncthreads();
    if (tid == 0) surprise[row] = (r3[0]+r3[1]+r3[2]+r3[3]) * (1.0f/H);
    short4 h4;
    h4.x = f2h(n.x); h4.y = f2h(n.y); h4.z = f2h(n.z); h4.w = f2h(n.w);
    ((short4*)(n16 + base))[tid] = h4;
  } else if (b < NTOK + 4096){
    int mrow = b - NTOK;
    long i = (long)mrow * 256 + tid;
    float4 x = ((const float4*)mem)[i];
    short4 h;
    h.x = f2h(x.x); h.y = f2h(x.y); h.z = f2h(x.z); h.w = f2h(x.w);
    ((short4*)m16)[i] = h;
    float4 b4 = ((const float4*)bq)[tid];
    float sb = b4.x*h2f(h.x) + b4.y*h2f(h.y) + b4.z*h2f(h.z) + b4.w*h2f(h.w);
    int wv = tid >> 6, lane = tid & 63;
    for (int o = 32; o; o >>= 1) sb += __shfl_down(sb, o);
    __shared__ float rb_[4];
    if (lane == 0) rb_[wv] = sb;
    __syncthreads();
    if (tid == 0) biasM[mrow] = rb_[0]+rb_[1]+rb_[2]+rb_[3];
  } else if (b < NTOK + 5120){
    long i = (long)(b - NTOK - 4096) * 256 + tid;
    float4 x = ((const float4*)Wo)[i];
    short4 h;
    h.x = f2h(x.x); h.y = f2h(x.y); h.z = f2h(x.z); h.w = f2h(x.w);
    ((short4*)wo16)[i] = h;
  } else {
    __shared__ __align__(16) short t[64][66];
    int tb = b - NTOK - 5120;              // 0..255
    int r0 = (tb >> 4) * 64, c0 = (tb & 15) * 64;
    #pragma unroll
    for (int k = 0; k < 4; ++k){
      int idx = k*256 + tid;
      int r = idx >> 4, c4 = (idx & 15) * 4;
      float4 x = *(const float4*)&Wq[(long)(r0+r)*H + c0 + c4];
      t[r][c4]   = f2h(x.x);
      t[r][c4+1] = f2h(x.y);
      t[r][c4+2] = f2h(x.z);
      t[r][c4+3] = f2h(x.w);
    }
    __syncthreads();
    #pragma unroll
    for (int k = 0; k < 4; ++k){
      int idx = k*256 + tid;
      int c = idx >> 4, r4 = (idx & 15) * 4;
      short4 h;
      h.x = t[r4][c]; h.y = t[r4+1][c]; h.z = t[r4+2][c]; h.w = t[r4+3][c];
      *(short4*)&wqT[(long)(c0+c)*H + r0 + r4] = h;
    }
  }
}

// ---------------- top-K level 1: per-256-chunk bitonic sort, emit top-64 ----------------
__global__ __launch_bounds__(256) void topk_local(
    const float* __restrict__ surprise, const float* __restrict__ imp,
    unsigned long long* __restrict__ cand_s, unsigned long long* __restrict__ cand_i)
{
  __shared__ unsigned long long s[256];
  int b = blockIdx.x, tid = threadIdx.x;
  int maxmode = (b < 32);
  int gidx = maxmode ? (b*256 + tid) : ((b-32)*256 + tid);
  float x = maxmode ? surprise[gidx] : imp[gidx];
  unsigned k = fkey_of(x);
  if (!maxmode) k = ~k;
  s[tid] = ((unsigned long long)k << 32) | (unsigned)(8191 - gidx);
  __syncthreads();
  for (int kk = 2; kk <= 256; kk <<= 1)
    for (int j = kk >> 1; j > 0; j >>= 1){
      int i = tid, ixj = i ^ j;
      if (ixj > i){
        bool asc = ((i & kk) == 0);
        unsigned long long a = s[i], c = s[ixj];
        if ((a < c) == asc){ s[i] = c; s[ixj] = a; }   // descending overall
      }
      __syncthreads();
    }
  if (tid < 64){
    if (maxmode) cand_s[b*64 + tid] = s[tid];
    else         cand_i[(b-32)*64 + tid] = s[tid];
  }
}

// ---------------- top-K level 2: merge candidates via bitonic sort ----------------
__global__ __launch_bounds__(256) void topk_merge(
    const unsigned long long* __restrict__ cand_s, const unsigned long long* __restrict__ cand_i,
    float* __restrict__ top_vals, int* __restrict__ top_idx, int* __restrict__ slots)
{
  __shared__ unsigned long long s[2048];
  int tid = threadIdx.x;
  int N = (blockIdx.x == 0) ? 2048 : 1024;
  const unsigned long long* src = (blockIdx.x == 0) ? cand_s : cand_i;
  for (int i = tid; i < N; i += 256) s[i] = src[i];
  __syncthreads();
  for (int kk = 2; kk <= N; kk <<= 1)
    for (int j = kk >> 1; j > 0; j >>= 1){
      for (int i = tid; i < N; i += 256){
        int ixj = i ^ j;
        if (ixj > i){
          bool asc = ((i & kk) == 0);
          unsigned long long a = s[i], c = s[ixj];
          if ((a < c) == asc){ s[i] = c; s[ixj] = a; }
        }
      }
      __syncthreads();
    }
  if (tid < 64){
    unsigned long long p = s[tid];
    int gi = 8191 - (int)(p & 0xffffffffu);
    if (blockIdx.x == 0){
      top_vals[tid] = val_of((unsigned)(p >> 32));
      top_idx[tid] = gi;
    } else {
      slots[tid] = gi;
    }
  }
}

// ---------------- top-K writes: recompute LN of selected rows, patch m16 + biasM ----------------
__global__ __launch_bounds__(256) void update_kernel(
    const float* __restrict__ top_vals, const int* __restrict__ top_idx, const int* __restrict__ slots,
    const float* __restrict__ hs, const float* __restrict__ g, const float* __restrict__ be,
    const float* __restrict__ bq,
    short* __restrict__ m16, float* __restrict__ biasM)
{
  int i = blockIdx.x;
  if (top_vals[i] <= FTHRESH) return;
  int s = slots[i], r = top_idx[i];
  int tid = threadIdx.x, w = tid >> 6, lane = tid & 63;
  long base = (long)r * H;
  float4 x = ((const float4*)(hs + base))[tid];
  float s1 = x.x + x.y + x.z + x.w;
  float s2 = x.x*x.x + x.y*x.y + x.z*x.z + x.w*x.w;
  __shared__ float r1[4], r2[4], rb[4];
  for (int o = 32; o; o >>= 1){ s1 += __shfl_down(s1, o); s2 += __shfl_down(s2, o); }
  if (lane == 0){ r1[w] = s1; r2[w] = s2; }
  __syncthreads();
  float S1 = r1[0]+r1[1]+r1[2]+r1[3];
  float S2 = r2[0]+r2[1]+r2[2]+r2[3];
  float mean = S1 * (1.0f/H);
  float var  = S2 * (1.0f/H) - mean*mean;
  float rinv = rsqrtf(var + 1e-12f);
  float4 gg = ((const float4*)g)[tid];
  float4 bb = ((const float4*)be)[tid];
  short4 h4;
  h4.x = f2h((x.x-mean)*rinv*gg.x + bb.x);
  h4.y = f2h((x.y-mean)*rinv*gg.y + bb.y);
  h4.z = f2h((x.z-mean)*rinv*gg.z + bb.z);
  h4.w = f2h((x.w-mean)*rinv*gg.w + bb.w);
  ((short4*)(m16 + (long)s*H))[tid] = h4;
  // biasM[s] = bq . fp16(new row)
  float4 b4 = ((const float4*)bq)[tid];
  float sb = b4.x*h2f(h4.x) + b4.y*h2f(h4.y) + b4.z*h2f(h4.z) + b4.w*h2f(h4.w);
  for (int o = 32; o; o >>= 1) sb += __shfl_down(sb, o);
  if (lane == 0) rb[w] = sb;
  __syncthreads();
  if (tid == 0) biasM[s] = rb[0]+rb[1]+rb[2]+rb[3];
}

// ---------------- dual 128x128-tile fp16 GEMM (m97 structure, 2 GEMMs 1 launch) ----------------
__global__ __launch_bounds__(256) void gemm_dual(
    const short* __restrict__ A0, const short* __restrict__ B0, int N0, short* __restrict__ O0,
    const short* __restrict__ A1, const short* __restrict__ B1, int N1, short* __restrict__ O1,
    int K)
{
  __shared__ short sA[128*64];
  __shared__ short sB[128*64];
  int tid = threadIdx.x, w = tid >> 6, lane = tid & 63, ln = lane & 15, quad = lane >> 4;
  int wr = w >> 1, wc = w & 1;
  int lin = blockIdx.x;                       // [0,512)
  int nl  = (lin & 7) * 64 + (lin >> 3);      // bijective XCD swizzle
  int second = (nl >= 256);
  int t = second ? (nl - 256) : nl;
  const short* A = second ? A1 : A0;
  const short* B = second ? B1 : B0;
  short* O = second ? O1 : O0;
  int N = second ? N1 : N0;
  int nwgx = N >> 7;
  long m0 = (long)(t / nwgx) * 128, n0 = (long)(t % nwgx) * 128;
  long Kl = K;
  vf4 acc[4][4];
  #pragma unroll
  for (int i = 0; i < 4; ++i) for (int j = 0; j < 4; ++j) for (int r = 0; r < 4; ++r) acc[i][j][r] = 0.0f;

  for (long kk = 0; kk < Kl; kk += 64){
    #pragma unroll
    for (int j = 0; j < 4; ++j){
      int f = (w*4 + j)*64 + lane;            // 16B-chunk id in [0,1024)
      int row = f >> 3, c8 = f & 7;
      long go = kk + (long)((c8 ^ (row & 7)) * 8);   // XOR-swizzled source chunk
      gload_lds16(A + (m0+row)*Kl + go, sA + (w*4+j)*512);
      gload_lds16(B + (n0+row)*Kl + go, sB + (w*4+j)*512);
    }
    __syncthreads();
    #pragma unroll
    for (int ks = 0; ks < 64; ks += 32){
      int cbase = (ks >> 3) + quad;
      half8 bh[4];
      #pragma unroll
      for (int j = 0; j < 4; ++j){
        int rb = wc*64 + j*16 + ln;
        bh[j] = *(const half8*)&sB[rb*64 + (cbase ^ (rb & 7))*8];
      }
      #pragma unroll
      for (int i = 0; i < 4; ++i){
        int ra = wr*64 + i*16 + ln;
        half8 a = *(const half8*)&sA[ra*64 + (cbase ^ (ra & 7))*8];
        #pragma unroll
        for (int j = 0; j < 4; ++j)
          acc[i][j] = __builtin_amdgcn_mfma_f32_16x16x32_f16(a, bh[j], acc[i][j], 0, 0, 0);
      }
    }
    __syncthreads();
  }

  #pragma unroll
  for (int i = 0; i < 4; ++i)
    #pragma unroll
    for (int j = 0; j < 4; ++j)
      #pragma unroll
      for (int r = 0; r < 4; ++r){
        long row = m0 + wr*64 + i*16 + quad*4 + r;
        long col = n0 + wc*64 + j*16 + ln;
        O[row*(long)N + col] = f2h(acc[i][j][r]);
      }
}

// ---------------- 256x256-tile 8-phase fp16 GEMM (T2+T3+T4+T5, frag reuse) ----------------
// SINGLE barrier per phase (invariant verified R6/R8, ref-checked).
// 8x8 XCD rectangle block map (R10: FETCH 80.8 -> 54 MB).
template<int MODE>
__global__ __launch_bounds__(512, 2) void gemm256(
    const short* __restrict__ A, const short* __restrict__ B,
    int K, int N,
    short* __restrict__ O1, float* __restrict__ Of,
    const float* __restrict__ resid, const float* __restrict__ biasN)
{
  extern __shared__ short lds[];   // 65536 shorts = 128 KiB
  int tid = threadIdx.x, w = tid >> 6, lane = tid & 63, ln = lane & 15, quad = lane >> 4;
  int wr = w >> 2, wc = w & 3;     // 2 x 4 wave grid
  int nwgx = gridDim.x;
  int lin = blockIdx.y * nwgx + blockIdx.x;
  int xcd = lin & 7, ii = lin >> 3;                   // ii in [0,64)
  int mt = (xcd >> 1)*8 + (ii >> 3);                  // [0,32)
  int nt = (xcd & 1)*8 + (ii & 7);                    // [0,16)
  long m0 = (long)mt * 256, n0 = (long)nt * 256;
  long Kl = K;
  int NT = K >> 6;

  auto STAGE = [&](const short* __restrict__ G, long rowbase, long kt, short* ldsbase){
    #pragma unroll
    for (int i = 0; i < 2; ++i){
      int f = i*512 + tid;
      int row = f >> 3, c8 = f & 7;
      long go = kt + (long)((c8 ^ (row & 7)) * 8);
      gload_lds16(G + (rowbase + row)*Kl + go, ldsbase + i*4096 + w*512);
    }
  };
  auto LOADA = [&](half8 (&af)[4][2], const short* sAh){
    #pragma unroll
    for (int ks = 0; ks < 2; ++ks){
      int cbase = ks*4 + quad;
      #pragma unroll
      for (int i = 0; i < 4; ++i){
        int ra = wr*64 + i*16 + ln;
        af[i][ks] = *(const half8*)&sAh[ra*64 + (cbase ^ (ra & 7))*8];
      }
    }
  };
  auto LOADB = [&](half8 (&bf)[2][2], const short* sBh){
    #pragma unroll
    for (int ks = 0; ks < 2; ++ks){
      int cbase = ks*4 + quad;
      #pragma unroll
      for (int j = 0; j < 2; ++j){
        int rb = wc*32 + j*16 + ln;
        bf[j][ks] = *(const half8*)&sBh[rb*64 + (cbase ^ (rb & 7))*8];
      }
    }
  };

  vf4 acc[4][4][2];
  #pragma unroll
  for (int p = 0; p < 4; ++p)
    for (int i = 0; i < 4; ++i)
      for (int j = 0; j < 2; ++j)
        for (int r = 0; r < 4; ++r) acc[p][i][j][r] = 0.0f;

  {
    int t1 = (NT > 1) ? 1 : 0;
    STAGE(A, m0 + 0,   0, lds + 0);
    STAGE(B, n0 + 0,   0, lds + 16384);
    STAGE(B, n0 + 128, 0, lds + 16384 + 8192);
    STAGE(A, m0 + 128, 0, lds + 8192);
    STAGE(A, m0 + 0,   (long)t1*64, lds + 32768);
    STAGE(B, n0 + 0,   (long)t1*64, lds + 32768 + 16384);
  }
  asm volatile("s_waitcnt vmcnt(8)" ::: "memory");
  asm volatile("s_barrier" ::: "memory");

  #define PH_MID()  do { \
    asm volatile("s_waitcnt lgkmcnt(0)" ::: "memory"); \
    __builtin_amdgcn_sched_barrier(0); \
    __builtin_amdgcn_s_setprio(1); } while(0)
  #define PH_END() do { \
    __builtin_amdgcn_s_setprio(0); \
    asm volatile("s_waitcnt vmcnt(8)" ::: "memory"); \
    asm volatile("s_barrier" ::: "memory"); } while(0)
  #define MFMA16(ap, af, bf) do { \
    _Pragma("unroll") \
    for (int i = 0; i < 4; ++i){ \
      _Pragma("unroll") \
      for (int j = 0; j < 2; ++j){ \
        ap[i][j] = __builtin_amdgcn_mfma_f32_16x16x32_f16(af[i][0], bf[j][0], ap[i][j], 0, 0, 0); \
        ap[i][j] = __builtin_amdgcn_mfma_f32_16x16x32_f16(af[i][1], bf[j][1], ap[i][j], 0, 0, 0); \
      } \
    } } while(0)

  for (int t = 0; t < NT; ++t){
    int cur = t & 1;
    short* bA = lds + cur*32768;
    short* bB = bA + 16384;
    short* oA = lds + (cur^1)*32768;
    short* oB = oA + 16384;
    int t1 = t + 1; if (t1 >= NT) t1 -= NT;
    int t2 = t + 2; if (t2 >= NT) t2 -= NT;
    long kt1 = (long)t1 * 64, kt2 = (long)t2 * 64;
    half8 af[4][2], bf0[2][2], bf1[2][2];

    // phase 0: A0 x B0
    LOADA(af, bA);
    LOADB(bf0, bB);
    STAGE(B, n0 + 128, kt1, oB + 8192);   // B1(t+1)
    PH_MID();
    MFMA16(acc[0], af, bf0);
    PH_END();

    // phase 1: A0 x B1 (reuse af)
    LOADB(bf1, bB + 8192);
    STAGE(A, m0 + 128, kt1, oA + 8192);   // A1(t+1)
    PH_MID();
    MFMA16(acc[1], af, bf1);
    PH_END();

    // phase 2: A1 x B0 (reuse bf0)
    LOADA(af, bA + 8192);
    STAGE(A, m0 + 0, kt2, bA);            // A0(t+2) (slot dead since p0)
    PH_MID();
    MFMA16(acc[2], af, bf0);
    PH_END();

    // phase 3: A1 x B1 (reuse af, bf1; zero ds_reads)
    STAGE(B, n0 + 0, kt2, bB);            // B0(t+2) (slot dead since p0)
    PH_MID();
    MFMA16(acc[3], af, bf1);
    PH_END();
  }
  #undef PH_MID
  #undef PH_END
  #undef MFMA16

  float bn[2][2];
  if (MODE != 2){
    #pragma unroll
    for (int bh = 0; bh < 2; ++bh)
      for (int j = 0; j < 2; ++j)
        bn[bh][j] = biasN[n0 + bh*128 + wc*32 + j*16 + ln];
  }
  #pragma unroll
  for (int p = 0; p < 4; ++p){
    #pragma unroll
    for (int i = 0; i < 4; ++i){
      #pragma unroll
      for (int j = 0; j < 2; ++j){
        #pragma unroll
        for (int r = 0; r < 4; ++r){
          long row = m0 + (p >> 1)*128 + wr*64 + i*16 + quad*4 + r;
          long col = n0 + (p & 1)*128 + wc*32 + j*16 + ln;
          float v = acc[p][i][j][r];
          if (MODE == 1){
            O1[row*(long)N + col] = f2h(v + bn[p & 1][j]);
          } else if (MODE == 2){
            O1[row*(long)N + col] = f2h(v);
          } else {
            Of[row*(long)N + col] = v + resid[row*(long)N + col] + bn[p & 1][j];
          }
        }
      }
    }
  }
}

// ---------------- FUSED softmax + final GEMM: out = hs + softmax(sim) @ VWoT^T + bo ----------------
// A = RAW fp16 logits [NTOK][MMEM]. Each block's A rows are FULL softmax rows
// (K = MMEM), so softmax fuses: (1) pre-pass computes per-row max m_r and
// 1/z_r (1 MB, coalesced, re-read by main loop hits L2); fully drained via
// __syncthreads() BEFORE the pipelined prologue so the counted-vmcnt ledger
// sees only gload_lds. (2) af fragments are row-pure (all 8 elems of af[i]
// belong to row wr*32+i*16+ln) -> exp(x - m_r) applied in-register after
// lgkmcnt(0) (64 exp/K-tile/wave, VALU, overlaps MFMA). (3) 1/z_r folds into
// the fp32 epilogue. Replaces the separate softmax kernel entirely.
// Pipeline = R8-proven: 8-phase, single barrier/phase, vmcnt(6), depth-2.
__global__ __launch_bounds__(512, 2) void gemm_out(
    const short* __restrict__ A, const short* __restrict__ B,
    int K, int N,
    float* __restrict__ Of, const float* __restrict__ resid, const float* __restrict__ biasN)
{
  extern __shared__ short lds[];   // 49152 shorts = 96 KiB
  __shared__ float mrow[128], invz[128];
  int tid = threadIdx.x, w = tid >> 6, lane = tid & 63, ln = lane & 15, quad = lane >> 4;
  int wr = (w >> 2) & 1, wc = w & 3;
  int nwgx = gridDim.x, nwg = nwgx * gridDim.y;       // 4 x 64 = 256
  int lin = blockIdx.y * nwgx + blockIdx.x;
  int nl  = (lin & 7) * (nwg >> 3) + (lin >> 3);      // XCD swizzle
  long m0 = (long)(nl >> 2) * 128, n0 = (long)(nl & 3) * 256;
  long Kl = K;
  int NT = K >> 6;

  // ---- softmax pre-pass: per-row max + 1/sum(exp) over this block's 128 rows ----
  // wave w handles rows w*16..w*16+15; per row: 64 lanes x 8 coalesced half8 loads.
  for (int rr = 0; rr < 16; ++rr){
    int row = w*16 + rr;
    const half8* rp = (const half8*)(A + (m0 + row)*Kl);
    half8 v[8];
    #pragma unroll
    for (int c = 0; c < 8; ++c) v[c] = rp[lane + c*64];
    float mx = -1e30f;
    #pragma unroll
    for (int c = 0; c < 8; ++c)
      #pragma unroll
      for (int e = 0; e < 8; ++e) mx = fmaxf(mx, (float)v[c][e]);
    for (int o = 32; o; o >>= 1) mx = fmaxf(mx, __shfl_xor(mx, o));
    float s = 0.f;
    #pragma unroll
    for (int c = 0; c < 8; ++c)
      #pragma unroll
      for (int e = 0; e < 8; ++e) s += __expf((float)v[c][e] - mx);
    for (int o = 32; o; o >>= 1) s += __shfl_xor(s, o);
    if (lane == 0){ mrow[row] = mx; invz[row] = 1.0f / s; }
  }
  __syncthreads();   // drains ALL vmem/lds; pipelined ledger starts clean

  // per-lane row-max scalars for the af fragments (half h, frag i)
  float mv[2][2];
  #pragma unroll
  for (int h = 0; h < 2; ++h)
    for (int i = 0; i < 2; ++i)
      mv[h][i] = mrow[h*64 + wr*32 + i*16 + ln];

  auto STAGE_A = [&](long rowbase, long kt, short* dst){
    int f = tid;                               // 512 chunks = 64 rows x 8
    int row = f >> 3, c8 = f & 7;
    long go = kt + (long)((c8 ^ (row & 7)) * 8);
    gload_lds16(A + (rowbase + row)*Kl + go, dst + w*512);
  };
  auto STAGE_B = [&](long rowbase, long kt, short* dst){
    #pragma unroll
    for (int i = 0; i < 2; ++i){
      int f = i*512 + tid;                     // 1024 chunks = 128 rows x 8
      int row = f >> 3, c8 = f & 7;
      long go = kt + (long)((c8 ^ (row & 7)) * 8);
      gload_lds16(B + (rowbase + row)*Kl + go, dst + i*4096 + w*512);
    }
  };
  auto LOADA = [&](half8 (&af)[2][2], const short* sAh){
    #pragma unroll
    for (int ks = 0; ks < 2; ++ks){
      int cbase = ks*4 + quad;
      #pragma unroll
      for (int i = 0; i < 2; ++i){
        int ra = wr*32 + i*16 + ln;            // [0,64)
        af[i][ks] = *(const half8*)&sAh[ra*64 + (cbase ^ (ra & 7))*8];
      }
    }
  };
  auto LOADB = [&](half8 (&bf)[2][2], const short* sBh){
    #pragma unroll
    for (int ks = 0; ks < 2; ++ks){
      int cbase = ks*4 + quad;
      #pragma unroll
      for (int j = 0; j < 2; ++j){
        int rb = wc*32 + j*16 + ln;            // [0,128)
        bf[j][ks] = *(const half8*)&sBh[rb*64 + (cbase ^ (rb & 7))*8];
      }
    }
  };

  vf4 acc[4][2][2];
  #pragma unroll
  for (int p = 0; p < 4; ++p)
    for (int i = 0; i < 2; ++i)
      for (int j = 0; j < 2; ++j)
        for (int r = 0; r < 4; ++r) acc[p][i][j][r] = 0.0f;

  // buf layout (shorts): [Ah0:4096][Ah1:4096][Bh0:8192][Bh1:8192] = 24576/buf
  {
    int t1 = (NT > 1) ? 1 : 0;
    STAGE_A(m0 + 0,   0, lds + 0);                    // Ah0(0)  [1]
    STAGE_B(n0 + 0,   0, lds + 8192);                 // Bh0(0)  [2]
    STAGE_B(n0 + 128, 0, lds + 16384);                // Bh1(0)  [2]
    STAGE_A(m0 + 64,  0, lds + 4096);                 // Ah1(0)  [1]
    STAGE_A(m0 + 0,   (long)t1*64, lds + 24576);      // Ah0(1)  [1]
    STAGE_B(n0 + 0,   (long)t1*64, lds + 24576+8192); // Bh0(1)  [2]
  }
  asm volatile("s_waitcnt vmcnt(6)" ::: "memory");
  asm volatile("s_barrier" ::: "memory");

  #define FPH_MID()  do { \
    asm volatile("s_waitcnt lgkmcnt(0)" ::: "memory"); \
    __builtin_amdgcn_sched_barrier(0); \
    __builtin_amdgcn_s_setprio(1); } while(0)
  #define FPH_END() do { \
    __builtin_amdgcn_s_setprio(0); \
    asm volatile("s_waitcnt vmcnt(6)" ::: "memory"); \
    asm volatile("s_barrier" ::: "memory"); } while(0)
  #define EXPA(af, h) do { \
    _Pragma("unroll") \
    for (int i = 0; i < 2; ++i){ \
      _Pragma("unroll") \
      for (int ks = 0; ks < 2; ++ks){ \
        _Pragma("unroll") \
        for (int e = 0; e < 8; ++e){ \
          float f_ = (float)af[i][ks][e]; \
          af[i][ks][e] = (_Float16)__expf(f_ - mv[h][i]); \
        } \
      } \
    } } while(0)
  #define MFMA8(ap, af, bf) do { \
    _Pragma("unroll") \
    for (int i = 0; i < 2; ++i){ \
      _Pragma("unroll") \
      for (int j = 0; j < 2; ++j){ \
        ap[i][j] = __builtin_amdgcn_mfma_f32_16x16x32_f16(af[i][0], bf[j][0], ap[i][j], 0, 0, 0); \
        ap[i][j] = __builtin_amdgcn_mfma_f32_16x16x32_f16(af[i][1], bf[j][1], ap[i][j], 0, 0, 0); \
      } \
    } } while(0)

  for (int t = 0; t < NT; ++t){
    int cur = t & 1;
    short* bA = lds + cur*24576;
    short* oA = lds + (cur^1)*24576;
    int t1 = t + 1; if (t1 >= NT) t1 -= NT;
    int t2 = t + 2; if (t2 >= NT) t2 -= NT;
    long kt1 = (long)t1 * 64, kt2 = (long)t2 * 64;
    half8 af[2][2], bf0[2][2], bf1[2][2];

    // phase 0: exp(Ah0) x Bh0
    LOADA(af, bA);
    LOADB(bf0, bA + 8192);
    STAGE_B(n0 + 128, kt1, oA + 16384);   // Bh1(t+1)
    FPH_MID();
    EXPA(af, 0);
    MFMA8(acc[0], af, bf0);
    FPH_END();

    // phase 1: exp(Ah0) x Bh1 (reuse af, already exp'd)
    LOADB(bf1, bA + 16384);
    STAGE_A(m0 + 64, kt1, oA + 4096);     // Ah1(t+1)
    FPH_MID();
    MFMA8(acc[1], af, bf1);
    FPH_END();

    // phase 2: exp(Ah1) x Bh0 (reuse bf0)
    LOADA(af, bA + 4096);
    STAGE_A(m0 + 0, kt2, bA);             // Ah0(t+2) (slot read only at p0)
    FPH_MID();
    EXPA(af, 1);
    MFMA8(acc[2], af, bf0);
    FPH_END();

    // phase 3: exp(Ah1) x Bh1 (reuse af, bf1; zero ds_reads)
    STAGE_B(n0 + 0, kt2, bA + 8192);      // Bh0(t+2) (slot read only at p0)
    FPH_MID();
    MFMA8(acc[3], af, bf1);
    FPH_END();
  }
  #undef FPH_MID
  #undef FPH_END
  #undef EXPA
  #undef MFMA8

  float bn[2][2];
  #pragma unroll
  for (int bh = 0; bh < 2; ++bh)
    for (int j = 0; j < 2; ++j)
      bn[bh][j] = biasN[n0 + bh*128 + wc*32 + j*16 + ln];
  #pragma unroll
  for (int p = 0; p < 4; ++p){
    #pragma unroll
    for (int i = 0; i < 2; ++i){
      #pragma unroll
      for (int j = 0; j < 2; ++j){
        #pragma unroll
        for (int r = 0; r < 4; ++r){
          int lr = (p >> 1)*64 + wr*32 + i*16 + quad*4 + r;
          long row = m0 + lr;
          long col = n0 + (p & 1)*128 + wc*32 + j*16 + ln;
          Of[row*(long)N + col] = acc[p][i][j][r]*invz[lr] + resid[row*(long)N + col] + bn[p & 1][j];
        }
      }
    }
  }
}

extern "C" void kernel_launch(void* const* d_in, const int* in_sizes, int n_in,
                              void* d_out, int out_size, void* d_ws, size_t ws_size,
                              hipStream_t stream)
{
  const float* hs  = (const float*)d_in[0];
  const float* gam = (const float*)d_in[1];
  const float* bet = (const float*)d_in[2];
  const float* Wq  = (const float*)d_in[3];
  const float* bq  = (const float*)d_in[4];
  const float* Wo  = (const float*)d_in[5];
  const float* bo  = (const float*)d_in[6];
  const float* mem = (const float*)d_in[7];
  const float* imp = (const float*)d_in[8];
  float* out = (float*)d_out;

  char* ws = (char*)d_ws;
  short* n16   = (short*)(ws);                   // [0,16)   fp16 norm
  short* g16   = (short*)(ws + (16ull<<20));     // [16,24)  fp16 G = mem_upd @ Wq
  short* m16   = (short*)(ws + (32ull<<20));     // [32,40)  fp16 mem (patched)
  short* wqT   = (short*)(ws + (40ull<<20));     // [40,42)  fp16 Wq^T [h][o]
  short* simP  = (short*)(ws + (48ull<<20));     // [48,112) fp16 RAW logits (softmax fused into gemm_out)
  short* vwoT  = (short*)(ws + (112ull<<20));    // [112,120) fp16 VWoT[o][m]
  short* wo16  = (short*)(ws + (132ull<<20));    // [132,134)
  char*  tail  = ws + (134ull<<20);
  float* biasM    = (float*)tail;
  float* surprise = (float*)(tail + (64<<10));
  float* top_vals = (float*)(tail + (128<<10));
  int*   top_idx  = (int*)  (tail + (129<<10));
  int*   slots    = (int*)  (tail + (130<<10));
  unsigned long long* cand_s = (unsigned long long*)(tail + (132<<10));  // 16 KB
  unsigned long long* cand_i = (unsigned long long*)(tail + (148<<10));  // 8 KB

  static bool attr_done = false;
  if (!attr_done){
    (void)hipFuncSetAttribute(reinterpret_cast<const void*>(&gemm256<1>),
                              hipFuncAttributeMaxDynamicSharedMemorySize, 131072);
    (void)hipFuncSetAttribute(reinterpret_cast<const void*>(&gemm_out),
                              hipFuncAttributeMaxDynamicSharedMemorySize, 98304);
    attr_done = true;
  }

  // LN (8192 blocks) + prep (5376 blocks) fused: independent work, 1 launch
  ln_prep_kernel<<<NTOK + 5376, 256, 0, stream>>>(
      hs, gam, bet, mem, Wq, Wo, bq, n16, surprise, m16, wqT, wo16, biasM);
  topk_local<<<48, 256, 0, stream>>>(surprise, imp, cand_s, cand_i);
  topk_merge<<<2, 256, 0, stream>>>(cand_s, cand_i, top_vals, top_idx, slots);
  update_kernel<<<KTOP, 256, 0, stream>>>(top_vals, top_idx, slots, hs, gam, bet, bq, m16, biasM);
  // VWoT[o][m] = Wo[o][:].mem_upd[m][:]  and  G[m][h] = mem_upd[m][:].wqT[h][:]
  gemm_dual<<<512, 256, 0, stream>>>(
      wo16, m16, MMEM, vwoT,  m16, wqT, H, g16,  H);
  // sim = norm @ G^T + biasM  -- raw logits fp16 (no separate softmax pass)
  gemm256<1><<<dim3(16,32), 512, 131072, stream>>>(
      n16, g16, H, MMEM, simP, nullptr, nullptr, biasM);
  // out = hidden + softmax(sim) @ VWoT^T + bo   -- fused softmax + GEMM
  gemm_out<<<dim3(4, 64), 512, 98304, stream>>>(
      simP, vwoT, MMEM, H, out, hs, bo);
}

// Round 12
// 363.150 us; speedup vs baseline: 1.2563x; 1.2563x over previous
//
#include <hip/hip_runtime.h>

#define H 1024
#define MMEM 4096
#define NTOK 8192
#define KTOP 64
#define FTHRESH 0.5f

typedef _Float16 half8 __attribute__((ext_vector_type(8)));  // 8 f16 in 4 VGPRs
typedef float vf4 __attribute__((ext_vector_type(4)));       // MFMA f32 acc

__device__ __forceinline__ short f2h(float x){
  union { _Float16 h; short s; } u; u.h = (_Float16)x; return u.s;
}
__device__ __forceinline__ float h2f(short s){
  union { _Float16 h; short s; } u; u.s = s; return (float)u.h;
}
// order-preserving float->uint32 key (monotone increasing)
__device__ __forceinline__ unsigned fkey_of(float x){
  unsigned u = __float_as_uint(x);
  return (u & 0x80000000u) ? ~u : (u | 0x80000000u);
}
__device__ __forceinline__ float val_of(unsigned k){
  unsigned u = (k & 0x80000000u) ? (k & 0x7fffffffu) : ~k;
  return __uint_as_float(u);
}

// async global->LDS, 16B/lane; LDS dest is wave-uniform base + lane*16 (HW rule)
__device__ __forceinline__ void gload_lds16(const short* g, short* l){
  __builtin_amdgcn_global_load_lds(
      (const __attribute__((address_space(1))) unsigned int*)g,
      (__attribute__((address_space(3))) unsigned int*)l, 16, 0, 0);
}

// ---------------- fused LN+surprise AND prep (independent work, 1 launch) ----------------
__global__ __launch_bounds__(256) void ln_prep_kernel(
    const float* __restrict__ hs, const float* __restrict__ g, const float* __restrict__ be,
    const float* __restrict__ mem, const float* __restrict__ Wq, const float* __restrict__ Wo,
    const float* __restrict__ bq,
    short* __restrict__ n16, float* __restrict__ surprise,
    short* __restrict__ m16, short* __restrict__ wqT, short* __restrict__ wo16,
    float* __restrict__ biasM)
{
  int b = blockIdx.x, tid = threadIdx.x;
  if (b < NTOK){
    int row = b;
    long base = (long)row * H;
    float4 x = ((const float4*)(hs + base))[tid];
    float s1 = x.x + x.y + x.z + x.w;
    float s2 = x.x*x.x + x.y*x.y + x.z*x.z + x.w*x.w;
    __shared__ float r1[4], r2[4], r3[4];
    int w = tid >> 6, lane = tid & 63;
    for (int o = 32; o; o >>= 1){ s1 += __shfl_down(s1, o); s2 += __shfl_down(s2, o); }
    if (lane == 0){ r1[w] = s1; r2[w] = s2; }
    __syncthreads();
    float S1 = r1[0]+r1[1]+r1[2]+r1[3];
    float S2 = r2[0]+r2[1]+r2[2]+r2[3];
    float mean = S1 * (1.0f/H);
    float var  = S2 * (1.0f/H) - mean*mean;
    float rinv = rsqrtf(var + 1e-12f);
    float4 gg = ((const float4*)g)[tid];
    float4 bb = ((const float4*)be)[tid];
    float4 n;
    n.x = (x.x-mean)*rinv*gg.x + bb.x;
    n.y = (x.y-mean)*rinv*gg.y + bb.y;
    n.z = (x.z-mean)*rinv*gg.z + bb.z;
    n.w = (x.w-mean)*rinv*gg.w + bb.w;
    float sa = fabsf(n.x)+fabsf(n.y)+fabsf(n.z)+fabsf(n.w);
    for (int o = 32; o; o >>= 1) sa += __shfl_down(sa, o);
    if (lane == 0) r3[w] = sa;
    __syncthreads();
    if (tid == 0) surprise[row] = (r3[0]+r3[1]+r3[2]+r3[3]) * (1.0f/H);
    short4 h4;
    h4.x = f2h(n.x); h4.y = f2h(n.y); h4.z = f2h(n.z); h4.w = f2h(n.w);
    ((short4*)(n16 + base))[tid] = h4;
  } else if (b < NTOK + 4096){
    int mrow = b - NTOK;
    long i = (long)mrow * 256 + tid;
    float4 x = ((const float4*)mem)[i];
    short4 h;
    h.x = f2h(x.x); h.y = f2h(x.y); h.z = f2h(x.z); h.w = f2h(x.w);
    ((short4*)m16)[i] = h;
    float4 b4 = ((const float4*)bq)[tid];
    float sb = b4.x*h2f(h.x) + b4.y*h2f(h.y) + b4.z*h2f(h.z) + b4.w*h2f(h.w);
    int wv = tid >> 6, lane = tid & 63;
    for (int o = 32; o; o >>= 1) sb += __shfl_down(sb, o);
    __shared__ float rb_[4];
    if (lane == 0) rb_[wv] = sb;
    __syncthreads();
    if (tid == 0) biasM[mrow] = rb_[0]+rb_[1]+rb_[2]+rb_[3];
  } else if (b < NTOK + 5120){
    long i = (long)(b - NTOK - 4096) * 256 + tid;
    float4 x = ((const float4*)Wo)[i];
    short4 h;
    h.x = f2h(x.x); h.y = f2h(x.y); h.z = f2h(x.z); h.w = f2h(x.w);
    ((short4*)wo16)[i] = h;
  } else {
    __shared__ __align__(16) short t[64][66];
    int tb = b - NTOK - 5120;              // 0..255
    int r0 = (tb >> 4) * 64, c0 = (tb & 15) * 64;
    #pragma unroll
    for (int k = 0; k < 4; ++k){
      int idx = k*256 + tid;
      int r = idx >> 4, c4 = (idx & 15) * 4;
      float4 x = *(const float4*)&Wq[(long)(r0+r)*H + c0 + c4];
      t[r][c4]   = f2h(x.x);
      t[r][c4+1] = f2h(x.y);
      t[r][c4+2] = f2h(x.z);
      t[r][c4+3] = f2h(x.w);
    }
    __syncthreads();
    #pragma unroll
    for (int k = 0; k < 4; ++k){
      int idx = k*256 + tid;
      int c = idx >> 4, r4 = (idx & 15) * 4;
      short4 h;
      h.x = t[r4][c]; h.y = t[r4+1][c]; h.z = t[r4+2][c]; h.w = t[r4+3][c];
      *(short4*)&wqT[(long)(c0+c)*H + r0 + r4] = h;
    }
  }
}

// ---------------- top-K level 1: per-256-chunk bitonic sort, emit top-64 ----------------
__global__ __launch_bounds__(256) void topk_local(
    const float* __restrict__ surprise, const float* __restrict__ imp,
    unsigned long long* __restrict__ cand_s, unsigned long long* __restrict__ cand_i)
{
  __shared__ unsigned long long s[256];
  int b = blockIdx.x, tid = threadIdx.x;
  int maxmode = (b < 32);
  int gidx = maxmode ? (b*256 + tid) : ((b-32)*256 + tid);
  float x = maxmode ? surprise[gidx] : imp[gidx];
  unsigned k = fkey_of(x);
  if (!maxmode) k = ~k;
  s[tid] = ((unsigned long long)k << 32) | (unsigned)(8191 - gidx);
  __syncthreads();
  for (int kk = 2; kk <= 256; kk <<= 1)
    for (int j = kk >> 1; j > 0; j >>= 1){
      int i = tid, ixj = i ^ j;
      if (ixj > i){
        bool asc = ((i & kk) == 0);
        unsigned long long a = s[i], c = s[ixj];
        if ((a < c) == asc){ s[i] = c; s[ixj] = a; }   // descending overall
      }
      __syncthreads();
    }
  if (tid < 64){
    if (maxmode) cand_s[b*64 + tid] = s[tid];
    else         cand_i[(b-32)*64 + tid] = s[tid];
  }
}

// ---------------- top-K level 2: merge candidates via bitonic sort ----------------
__global__ __launch_bounds__(256) void topk_merge(
    const unsigned long long* __restrict__ cand_s, const unsigned long long* __restrict__ cand_i,
    float* __restrict__ top_vals, int* __restrict__ top_idx, int* __restrict__ slots)
{
  __shared__ unsigned long long s[2048];
  int tid = threadIdx.x;
  int N = (blockIdx.x == 0) ? 2048 : 1024;
  const unsigned long long* src = (blockIdx.x == 0) ? cand_s : cand_i;
  for (int i = tid; i < N; i += 256) s[i] = src[i];
  __syncthreads();
  for (int kk = 2; kk <= N; kk <<= 1)
    for (int j = kk >> 1; j > 0; j >>= 1){
      for (int i = tid; i < N; i += 256){
        int ixj = i ^ j;
        if (ixj > i){
          bool asc = ((i & kk) == 0);
          unsigned long long a = s[i], c = s[ixj];
          if ((a < c) == asc){ s[i] = c; s[ixj] = a; }
        }
      }
      __syncthreads();
    }
  if (tid < 64){
    unsigned long long p = s[tid];
    int gi = 8191 - (int)(p & 0xffffffffu);
    if (blockIdx.x == 0){
      top_vals[tid] = val_of((unsigned)(p >> 32));
      top_idx[tid] = gi;
    } else {
      slots[tid] = gi;
    }
  }
}

// ---------------- top-K writes: recompute LN of selected rows, patch m16 + biasM ----------------
__global__ __launch_bounds__(256) void update_kernel(
    const float* __restrict__ top_vals, const int* __restrict__ top_idx, const int* __restrict__ slots,
    const float* __restrict__ hs, const float* __restrict__ g, const float* __restrict__ be,
    const float* __restrict__ bq,
    short* __restrict__ m16, float* __restrict__ biasM)
{
  int i = blockIdx.x;
  if (top_vals[i] <= FTHRESH) return;
  int s = slots[i], r = top_idx[i];
  int tid = threadIdx.x, w = tid >> 6, lane = tid & 63;
  long base = (long)r * H;
  float4 x = ((const float4*)(hs + base))[tid];
  float s1 = x.x + x.y + x.z + x.w;
  float s2 = x.x*x.x + x.y*x.y + x.z*x.z + x.w*x.w;
  __shared__ float r1[4], r2[4], rb[4];
  for (int o = 32; o; o >>= 1){ s1 += __shfl_down(s1, o); s2 += __shfl_down(s2, o); }
  if (lane == 0){ r1[w] = s1; r2[w] = s2; }
  __syncthreads();
  float S1 = r1[0]+r1[1]+r1[2]+r1[3];
  float S2 = r2[0]+r2[1]+r2[2]+r2[3];
  float mean = S1 * (1.0f/H);
  float var  = S2 * (1.0f/H) - mean*mean;
  float rinv = rsqrtf(var + 1e-12f);
  float4 gg = ((const float4*)g)[tid];
  float4 bb = ((const float4*)be)[tid];
  short4 h4;
  h4.x = f2h((x.x-mean)*rinv*gg.x + bb.x);
  h4.y = f2h((x.y-mean)*rinv*gg.y + bb.y);
  h4.z = f2h((x.z-mean)*rinv*gg.z + bb.z);
  h4.w = f2h((x.w-mean)*rinv*gg.w + bb.w);
  ((short4*)(m16 + (long)s*H))[tid] = h4;
  // biasM[s] = bq . fp16(new row)
  float4 b4 = ((const float4*)bq)[tid];
  float sb = b4.x*h2f(h4.x) + b4.y*h2f(h4.y) + b4.z*h2f(h4.z) + b4.w*h2f(h4.w);
  for (int o = 32; o; o >>= 1) sb += __shfl_down(sb, o);
  if (lane == 0) rb[w] = sb;
  __syncthreads();
  if (tid == 0) biasM[s] = rb[0]+rb[1]+rb[2]+rb[3];
}

// ---------------- dual GEMM via the PROVEN gemm_out 8-phase body ----------------
// 256 blocks x 512 thr = 1 wg/CU. After XCD swizzle, q in [0,128): VWoT
// (A=wo16 M=1024, B=m16 N=4096; 8 m-tiles x 16 n-tiles, m-major);
// q in [128,256): G (A=m16 M=4096, B=wqT N=1024; 32 x 4, m-major).
// fp16 epilogue, no bias/resid. Body/ledger identical to gemm_out (R8-proven:
// BM=128/BN=256/BK=64, single barrier/phase, vmcnt(6), depth-2, frag reuse).
// Per-element K-accumulation order identical to the old gemm_dual -> bitwise
// identical outputs.
__global__ __launch_bounds__(512, 2) void gemm_dual2(
    const short* __restrict__ A0, const short* __restrict__ B0,   // VWoT operands
    const short* __restrict__ A1, const short* __restrict__ B1,   // G operands
    short* __restrict__ O0, short* __restrict__ O1v,
    int K)
{
  extern __shared__ short lds[];   // 49152 shorts = 96 KiB
  int tid = threadIdx.x, w = tid >> 6, lane = tid & 63, ln = lane & 15, quad = lane >> 4;
  int wr = (w >> 2) & 1, wc = w & 3;
  int lin = blockIdx.x;                               // [0,256)
  int nl  = (lin & 7) * 32 + (lin >> 3);              // bijective XCD swizzle
  int second = (nl >= 128);
  int q = second ? (nl - 128) : nl;
  const short* A = second ? A1 : A0;
  const short* B = second ? B1 : B0;
  short* O = second ? O1v : O0;
  int N = second ? H : MMEM;
  long m0, n0;
  if (second){ m0 = (long)(q >> 2) * 128; n0 = (long)(q & 3) * 256; }   // 32 x 4
  else       { m0 = (long)(q >> 4) * 128; n0 = (long)(q & 15) * 256; }  // 8 x 16
  long Kl = K;
  int NT = K >> 6;

  auto STAGE_A = [&](long rowbase, long kt, short* dst){
    int f = tid;                               // 512 chunks = 64 rows x 8
    int row = f >> 3, c8 = f & 7;
    long go = kt + (long)((c8 ^ (row & 7)) * 8);
    gload_lds16(A + (rowbase + row)*Kl + go, dst + w*512);
  };
  auto STAGE_B = [&](long rowbase, long kt, short* dst){
    #pragma unroll
    for (int i = 0; i < 2; ++i){
      int f = i*512 + tid;                     // 1024 chunks = 128 rows x 8
      int row = f >> 3, c8 = f & 7;
      long go = kt + (long)((c8 ^ (row & 7)) * 8);
      gload_lds16(B + (rowbase + row)*Kl + go, dst + i*4096 + w*512);
    }
  };
  auto LOADA = [&](half8 (&af)[2][2], const short* sAh){
    #pragma unroll
    for (int ks = 0; ks < 2; ++ks){
      int cbase = ks*4 + quad;
      #pragma unroll
      for (int i = 0; i < 2; ++i){
        int ra = wr*32 + i*16 + ln;            // [0,64)
        af[i][ks] = *(const half8*)&sAh[ra*64 + (cbase ^ (ra & 7))*8];
      }
    }
  };
  auto LOADB = [&](half8 (&bf)[2][2], const short* sBh){
    #pragma unroll
    for (int ks = 0; ks < 2; ++ks){
      int cbase = ks*4 + quad;
      #pragma unroll
      for (int j = 0; j < 2; ++j){
        int rb = wc*32 + j*16 + ln;            // [0,128)
        bf[j][ks] = *(const half8*)&sBh[rb*64 + (cbase ^ (rb & 7))*8];
      }
    }
  };

  vf4 acc[4][2][2];
  #pragma unroll
  for (int p = 0; p < 4; ++p)
    for (int i = 0; i < 2; ++i)
      for (int j = 0; j < 2; ++j)
        for (int r = 0; r < 4; ++r) acc[p][i][j][r] = 0.0f;

  // buf layout (shorts): [Ah0:4096][Ah1:4096][Bh0:8192][Bh1:8192] = 24576/buf
  {
    int t1 = (NT > 1) ? 1 : 0;
    STAGE_A(m0 + 0,   0, lds + 0);                    // Ah0(0)  [1]
    STAGE_B(n0 + 0,   0, lds + 8192);                 // Bh0(0)  [2]
    STAGE_B(n0 + 128, 0, lds + 16384);                // Bh1(0)  [2]
    STAGE_A(m0 + 64,  0, lds + 4096);                 // Ah1(0)  [1]
    STAGE_A(m0 + 0,   (long)t1*64, lds + 24576);      // Ah0(1)  [1]
    STAGE_B(n0 + 0,   (long)t1*64, lds + 24576+8192); // Bh0(1)  [2]
  }
  asm volatile("s_waitcnt vmcnt(6)" ::: "memory");
  asm volatile("s_barrier" ::: "memory");

  #define DPH_MID()  do { \
    asm volatile("s_waitcnt lgkmcnt(0)" ::: "memory"); \
    __builtin_amdgcn_sched_barrier(0); \
    __builtin_amdgcn_s_setprio(1); } while(0)
  #define DPH_END() do { \
    __builtin_amdgcn_s_setprio(0); \
    asm volatile("s_waitcnt vmcnt(6)" ::: "memory"); \
    asm volatile("s_barrier" ::: "memory"); } while(0)
  #define DMFMA8(ap, af, bf) do { \
    _Pragma("unroll") \
    for (int i = 0; i < 2; ++i){ \
      _Pragma("unroll") \
      for (int j = 0; j < 2; ++j){ \
        ap[i][j] = __builtin_amdgcn_mfma_f32_16x16x32_f16(af[i][0], bf[j][0], ap[i][j], 0, 0, 0); \
        ap[i][j] = __builtin_amdgcn_mfma_f32_16x16x32_f16(af[i][1], bf[j][1], ap[i][j], 0, 0, 0); \
      } \
    } } while(0)

  for (int t = 0; t < NT; ++t){
    int cur = t & 1;
    short* bA = lds + cur*24576;
    short* oA = lds + (cur^1)*24576;
    int t1 = t + 1; if (t1 >= NT) t1 -= NT;
    int t2 = t + 2; if (t2 >= NT) t2 -= NT;
    long kt1 = (long)t1 * 64, kt2 = (long)t2 * 64;
    half8 af[2][2], bf0[2][2], bf1[2][2];

    // phase 0: Ah0 x Bh0
    LOADA(af, bA);
    LOADB(bf0, bA + 8192);
    STAGE_B(n0 + 128, kt1, oA + 16384);   // Bh1(t+1)
    DPH_MID();
    DMFMA8(acc[0], af, bf0);
    DPH_END();

    // phase 1: Ah0 x Bh1 (reuse af)
    LOADB(bf1, bA + 16384);
    STAGE_A(m0 + 64, kt1, oA + 4096);     // Ah1(t+1)
    DPH_MID();
    DMFMA8(acc[1], af, bf1);
    DPH_END();

    // phase 2: Ah1 x Bh0 (reuse bf0)
    LOADA(af, bA + 4096);
    STAGE_A(m0 + 0, kt2, bA);             // Ah0(t+2) (slot read only at p0)
    DPH_MID();
    DMFMA8(acc[2], af, bf0);
    DPH_END();

    // phase 3: Ah1 x Bh1 (reuse af, bf1; zero ds_reads)
    STAGE_B(n0 + 0, kt2, bA + 8192);      // Bh0(t+2) (slot read only at p0)
    DPH_MID();
    DMFMA8(acc[3], af, bf1);
    DPH_END();
  }
  #undef DPH_MID
  #undef DPH_END
  #undef DMFMA8

  #pragma unroll
  for (int p = 0; p < 4; ++p){
    #pragma unroll
    for (int i = 0; i < 2; ++i){
      #pragma unroll
      for (int j = 0; j < 2; ++j){
        #pragma unroll
        for (int r = 0; r < 4; ++r){
          long row = m0 + (p >> 1)*64 + wr*32 + i*16 + quad*4 + r;
          long col = n0 + (p & 1)*128 + wc*32 + j*16 + ln;
          O[row*(long)N + col] = f2h(acc[p][i][j][r]);
        }
      }
    }
  }
}

// ---------------- 256x256-tile 8-phase fp16 GEMM (T2+T3+T4+T5, frag reuse) ----------------
// SINGLE barrier per phase (invariant verified R6/R8, ref-checked).
// 8x8 XCD rectangle block map (R10: FETCH 80.8 -> 54 MB).
template<int MODE>
__global__ __launch_bounds__(512, 2) void gemm256(
    const short* __restrict__ A, const short* __restrict__ B,
    int K, int N,
    short* __restrict__ O1, float* __restrict__ Of,
    const float* __restrict__ resid, const float* __restrict__ biasN)
{
  extern __shared__ short lds[];   // 65536 shorts = 128 KiB
  int tid = threadIdx.x, w = tid >> 6, lane = tid & 63, ln = lane & 15, quad = lane >> 4;
  int wr = w >> 2, wc = w & 3;     // 2 x 4 wave grid
  int nwgx = gridDim.x;
  int lin = blockIdx.y * nwgx + blockIdx.x;
  int xcd = lin & 7, ii = lin >> 3;                   // ii in [0,64)
  int mt = (xcd >> 1)*8 + (ii >> 3);                  // [0,32)
  int nt = (xcd & 1)*8 + (ii & 7);                    // [0,16)
  long m0 = (long)mt * 256, n0 = (long)nt * 256;
  long Kl = K;
  int NT = K >> 6;

  auto STAGE = [&](const short* __restrict__ G, long rowbase, long kt, short* ldsbase){
    #pragma unroll
    for (int i = 0; i < 2; ++i){
      int f = i*512 + tid;
      int row = f >> 3, c8 = f & 7;
      long go = kt + (long)((c8 ^ (row & 7)) * 8);
      gload_lds16(G + (rowbase + row)*Kl + go, ldsbase + i*4096 + w*512);
    }
  };
  auto LOADA = [&](half8 (&af)[4][2], const short* sAh){
    #pragma unroll
    for (int ks = 0; ks < 2; ++ks){
      int cbase = ks*4 + quad;
      #pragma unroll
      for (int i = 0; i < 4; ++i){
        int ra = wr*64 + i*16 + ln;
        af[i][ks] = *(const half8*)&sAh[ra*64 + (cbase ^ (ra & 7))*8];
      }
    }
  };
  auto LOADB = [&](half8 (&bf)[2][2], const short* sBh){
    #pragma unroll
    for (int ks = 0; ks < 2; ++ks){
      int cbase = ks*4 + quad;
      #pragma unroll
      for (int j = 0; j < 2; ++j){
        int rb = wc*32 + j*16 + ln;
        bf[j][ks] = *(const half8*)&sBh[rb*64 + (cbase ^ (rb & 7))*8];
      }
    }
  };

  vf4 acc[4][4][2];
  #pragma unroll
  for (int p = 0; p < 4; ++p)
    for (int i = 0; i < 4; ++i)
      for (int j = 0; j < 2; ++j)
        for (int r = 0; r < 4; ++r) acc[p][i][j][r] = 0.0f;

  {
    int t1 = (NT > 1) ? 1 : 0;
    STAGE(A, m0 + 0,   0, lds + 0);
    STAGE(B, n0 + 0,   0, lds + 16384);
    STAGE(B, n0 + 128, 0, lds + 16384 + 8192);
    STAGE(A, m0 + 128, 0, lds + 8192);
    STAGE(A, m0 + 0,   (long)t1*64, lds + 32768);
    STAGE(B, n0 + 0,   (long)t1*64, lds + 32768 + 16384);
  }
  asm volatile("s_waitcnt vmcnt(8)" ::: "memory");
  asm volatile("s_barrier" ::: "memory");

  #define PH_MID()  do { \
    asm volatile("s_waitcnt lgkmcnt(0)" ::: "memory"); \
    __builtin_amdgcn_sched_barrier(0); \
    __builtin_amdgcn_s_setprio(1); } while(0)
  #define PH_END() do { \
    __builtin_amdgcn_s_setprio(0); \
    asm volatile("s_waitcnt vmcnt(8)" ::: "memory"); \
    asm volatile("s_barrier" ::: "memory"); } while(0)
  #define MFMA16(ap, af, bf) do { \
    _Pragma("unroll") \
    for (int i = 0; i < 4; ++i){ \
      _Pragma("unroll") \
      for (int j = 0; j < 2; ++j){ \
        ap[i][j] = __builtin_amdgcn_mfma_f32_16x16x32_f16(af[i][0], bf[j][0], ap[i][j], 0, 0, 0); \
        ap[i][j] = __builtin_amdgcn_mfma_f32_16x16x32_f16(af[i][1], bf[j][1], ap[i][j], 0, 0, 0); \
      } \
    } } while(0)

  for (int t = 0; t < NT; ++t){
    int cur = t & 1;
    short* bA = lds + cur*32768;
    short* bB = bA + 16384;
    short* oA = lds + (cur^1)*32768;
    short* oB = oA + 16384;
    int t1 = t + 1; if (t1 >= NT) t1 -= NT;
    int t2 = t + 2; if (t2 >= NT) t2 -= NT;
    long kt1 = (long)t1 * 64, kt2 = (long)t2 * 64;
    half8 af[4][2], bf0[2][2], bf1[2][2];

    // phase 0: A0 x B0
    LOADA(af, bA);
    LOADB(bf0, bB);
    STAGE(B, n0 + 128, kt1, oB + 8192);   // B1(t+1)
    PH_MID();
    MFMA16(acc[0], af, bf0);
    PH_END();

    // phase 1: A0 x B1 (reuse af)
    LOADB(bf1, bB + 8192);
    STAGE(A, m0 + 128, kt1, oA + 8192);   // A1(t+1)
    PH_MID();
    MFMA16(acc[1], af, bf1);
    PH_END();

    // phase 2: A1 x B0 (reuse bf0)
    LOADA(af, bA + 8192);
    STAGE(A, m0 + 0, kt2, bA);            // A0(t+2) (slot dead since p0)
    PH_MID();
    MFMA16(acc[2], af, bf0);
    PH_END();

    // phase 3: A1 x B1 (reuse af, bf1; zero ds_reads)
    STAGE(B, n0 + 0, kt2, bB);            // B0(t+2) (slot dead since p0)
    PH_MID();
    MFMA16(acc[3], af, bf1);
    PH_END();
  }
  #undef PH_MID
  #undef PH_END
  #undef MFMA16

  float bn[2][2];
  if (MODE != 2){
    #pragma unroll
    for (int bh = 0; bh < 2; ++bh)
      for (int j = 0; j < 2; ++j)
        bn[bh][j] = biasN[n0 + bh*128 + wc*32 + j*16 + ln];
  }
  #pragma unroll
  for (int p = 0; p < 4; ++p){
    #pragma unroll
    for (int i = 0; i < 4; ++i){
      #pragma unroll
      for (int j = 0; j < 2; ++j){
        #pragma unroll
        for (int r = 0; r < 4; ++r){
          long row = m0 + (p >> 1)*128 + wr*64 + i*16 + quad*4 + r;
          long col = n0 + (p & 1)*128 + wc*32 + j*16 + ln;
          float v = acc[p][i][j][r];
          if (MODE == 1){
            O1[row*(long)N + col] = f2h(v + bn[p & 1][j]);
          } else if (MODE == 2){
            O1[row*(long)N + col] = f2h(v);
          } else {
            Of[row*(long)N + col] = v + resid[row*(long)N + col] + bn[p & 1][j];
          }
        }
      }
    }
  }
}

// ---------------- final GEMM: out = hs + P @ VWoT^T + bo (R8-proven body) ----------------
// BM=128 x BN=256 x BK=64, 8-phase counted-vmcnt, SINGLE barrier per phase.
// vmcnt(6). Block map m-major within XCD (A-panel-contiguous; FETCH 83.5 MB).
__global__ __launch_bounds__(512, 2) void gemm_out(
    const short* __restrict__ A, const short* __restrict__ B,
    int K, int N,
    float* __restrict__ Of, const float* __restrict__ resid, const float* __restrict__ biasN)
{
  extern __shared__ short lds[];   // 49152 shorts = 96 KiB
  int tid = threadIdx.x, w = tid >> 6, lane = tid & 63, ln = lane & 15, quad = lane >> 4;
  int wr = (w >> 2) & 1, wc = w & 3;
  int nwgx = gridDim.x, nwg = nwgx * gridDim.y;       // 4 x 64 = 256
  int lin = blockIdx.y * nwgx + blockIdx.x;
  int nl  = (lin & 7) * (nwg >> 3) + (lin >> 3);      // XCD swizzle
  long m0 = (long)(nl >> 2) * 128, n0 = (long)(nl & 3) * 256;
  long Kl = K;
  int NT = K >> 6;

  auto STAGE_A = [&](long rowbase, long kt, short* dst){
    int f = tid;                               // 512 chunks = 64 rows x 8
    int row = f >> 3, c8 = f & 7;
    long go = kt + (long)((c8 ^ (row & 7)) * 8);
    gload_lds16(A + (rowbase + row)*Kl + go, dst + w*512);
  };
  auto STAGE_B = [&](long rowbase, long kt, short* dst){
    #pragma unroll
    for (int i = 0; i < 2; ++i){
      int f = i*512 + tid;                     // 1024 chunks = 128 rows x 8
      int row = f >> 3, c8 = f & 7;
      long go = kt + (long)((c8 ^ (row & 7)) * 8);
      gload_lds16(B + (rowbase + row)*Kl + go, dst + i*4096 + w*512);
    }
  };
  auto LOADA = [&](half8 (&af)[2][2], const short* sAh){
    #pragma unroll
    for (int ks = 0; ks < 2; ++ks){
      int cbase = ks*4 + quad;
      #pragma unroll
      for (int i = 0; i < 2; ++i){
        int ra = wr*32 + i*16 + ln;            // [0,64)
        af[i][ks] = *(const half8*)&sAh[ra*64 + (cbase ^ (ra & 7))*8];
      }
    }
  };
  auto LOADB = [&](half8 (&bf)[2][2], const short* sBh){
    #pragma unroll
    for (int ks = 0; ks < 2; ++ks){
      int cbase = ks*4 + quad;
      #pragma unroll
      for (int j = 0; j < 2; ++j){
        int rb = wc*32 + j*16 + ln;            // [0,128)
        bf[j][ks] = *(const half8*)&sBh[rb*64 + (cbase ^ (rb & 7))*8];
      }
    }
  };

  vf4 acc[4][2][2];
  #pragma unroll
  for (int p = 0; p < 4; ++p)
    for (int i = 0; i < 2; ++i)
      for (int j = 0; j < 2; ++j)
        for (int r = 0; r < 4; ++r) acc[p][i][j][r] = 0.0f;

  // buf layout (shorts): [Ah0:4096][Ah1:4096][Bh0:8192][Bh1:8192] = 24576/buf
  {
    int t1 = (NT > 1) ? 1 : 0;
    STAGE_A(m0 + 0,   0, lds + 0);                    // Ah0(0)  [1]
    STAGE_B(n0 + 0,   0, lds + 8192);                 // Bh0(0)  [2]
    STAGE_B(n0 + 128, 0, lds + 16384);                // Bh1(0)  [2]
    STAGE_A(m0 + 64,  0, lds + 4096);                 // Ah1(0)  [1]
    STAGE_A(m0 + 0,   (long)t1*64, lds + 24576);      // Ah0(1)  [1]
    STAGE_B(n0 + 0,   (long)t1*64, lds + 24576+8192); // Bh0(1)  [2]
  }
  asm volatile("s_waitcnt vmcnt(6)" ::: "memory");
  asm volatile("s_barrier" ::: "memory");

  #define FPH_MID()  do { \
    asm volatile("s_waitcnt lgkmcnt(0)" ::: "memory"); \
    __builtin_amdgcn_sched_barrier(0); \
    __builtin_amdgcn_s_setprio(1); } while(0)
  #define FPH_END() do { \
    __builtin_amdgcn_s_setprio(0); \
    asm volatile("s_waitcnt vmcnt(6)" ::: "memory"); \
    asm volatile("s_barrier" ::: "memory"); } while(0)
  #define MFMA8(ap, af, bf) do { \
    _Pragma("unroll") \
    for (int i = 0; i < 2; ++i){ \
      _Pragma("unroll") \
      for (int j = 0; j < 2; ++j){ \
        ap[i][j] = __builtin_amdgcn_mfma_f32_16x16x32_f16(af[i][0], bf[j][0], ap[i][j], 0, 0, 0); \
        ap[i][j] = __builtin_amdgcn_mfma_f32_16x16x32_f16(af[i][1], bf[j][1], ap[i][j], 0, 0, 0); \
      } \
    } } while(0)

  for (int t = 0; t < NT; ++t){
    int cur = t & 1;
    short* bA = lds + cur*24576;
    short* oA = lds + (cur^1)*24576;
    int t1 = t + 1; if (t1 >= NT) t1 -= NT;
    int t2 = t + 2; if (t2 >= NT) t2 -= NT;
    long kt1 = (long)t1 * 64, kt2 = (long)t2 * 64;
    half8 af[2][2], bf0[2][2], bf1[2][2];

    // phase 0: Ah0 x Bh0
    LOADA(af, bA);
    LOADB(bf0, bA + 8192);
    STAGE_B(n0 + 128, kt1, oA + 16384);   // Bh1(t+1)
    FPH_MID();
    MFMA8(acc[0], af, bf0);
    FPH_END();

    // phase 1: Ah0 x Bh1 (reuse af)
    LOADB(bf1, bA + 16384);
    STAGE_A(m0 + 64, kt1, oA + 4096);     // Ah1(t+1)
    FPH_MID();
    MFMA8(acc[1], af, bf1);
    FPH_END();

    // phase 2: Ah1 x Bh0 (reuse bf0)
    LOADA(af, bA + 4096);
    STAGE_A(m0 + 0, kt2, bA);             // Ah0(t+2) (slot read only at p0)
    FPH_MID();
    MFMA8(acc[2], af, bf0);
    FPH_END();

    // phase 3: Ah1 x Bh1 (reuse af, bf1; zero ds_reads)
    STAGE_B(n0 + 0, kt2, bA + 8192);      // Bh0(t+2) (slot read only at p0)
    FPH_MID();
    MFMA8(acc[3], af, bf1);
    FPH_END();
  }
  #undef FPH_MID
  #undef FPH_END
  #undef MFMA8

  float bn[2][2];
  #pragma unroll
  for (int bh = 0; bh < 2; ++bh)
    for (int j = 0; j < 2; ++j)
      bn[bh][j] = biasN[n0 + bh*128 + wc*32 + j*16 + ln];
  #pragma unroll
  for (int p = 0; p < 4; ++p){
    #pragma unroll
    for (int i = 0; i < 2; ++i){
      #pragma unroll
      for (int j = 0; j < 2; ++j){
        #pragma unroll
        for (int r = 0; r < 4; ++r){
          long row = m0 + (p >> 1)*64 + wr*32 + i*16 + quad*4 + r;
          long col = n0 + (p & 1)*128 + wc*32 + j*16 + ln;
          Of[row*(long)N + col] = acc[p][i][j][r] + resid[row*(long)N + col] + bn[p & 1][j];
        }
      }
    }
  }
}

// ---------------- row softmax in-place: sim fp16 [NTOK][MMEM] -> P fp16 ----------------
__global__ __launch_bounds__(256) void softmax_kernel(short* __restrict__ simP)
{
  long row = blockIdx.x;
  int tid = threadIdx.x, w = tid >> 6, lane = tid & 63;
  half8* ptr = (half8*)(simP + row*MMEM);
  float xf[16];
  float mx = -1e30f;
  #pragma unroll
  for (int j = 0; j < 2; ++j){
    half8 x = ptr[tid + j*256];
    #pragma unroll
    for (int e = 0; e < 8; ++e){ float f = (float)x[e]; xf[j*8+e] = f; mx = fmaxf(mx, f); }
  }
  for (int o = 32; o; o >>= 1) mx = fmaxf(mx, __shfl_xor(mx, o));
  __shared__ float rmax[4], rsum[4];
  if (lane == 0) rmax[w] = mx;
  __syncthreads();
  mx = fmaxf(fmaxf(rmax[0], rmax[1]), fmaxf(rmax[2], rmax[3]));
  float p[16], s = 0.f;
  #pragma unroll
  for (int k = 0; k < 16; ++k){ p[k] = __expf(xf[k] - mx); s += p[k]; }
  for (int o = 32; o; o >>= 1) s += __shfl_xor(s, o);
  if (lane == 0) rsum[w] = s;
  __syncthreads();
  float inv = 1.0f / (rsum[0]+rsum[1]+rsum[2]+rsum[3]);
  #pragma unroll
  for (int j = 0; j < 2; ++j){
    half8 o8;
    #pragma unroll
    for (int e = 0; e < 8; ++e) o8[e] = (_Float16)(p[j*8+e] * inv);
    ptr[tid + j*256] = o8;
  }
}

extern "C" void kernel_launch(void* const* d_in, const int* in_sizes, int n_in,
                              void* d_out, int out_size, void* d_ws, size_t ws_size,
                              hipStream_t stream)
{
  const float* hs  = (const float*)d_in[0];
  const float* gam = (const float*)d_in[1];
  const float* bet = (const float*)d_in[2];
  const float* Wq  = (const float*)d_in[3];
  const float* bq  = (const float*)d_in[4];
  const float* Wo  = (const float*)d_in[5];
  const float* bo  = (const float*)d_in[6];
  const float* mem = (const float*)d_in[7];
  const float* imp = (const float*)d_in[8];
  float* out = (float*)d_out;

  char* ws = (char*)d_ws;
  short* n16   = (short*)(ws);                   // [0,16)   fp16 norm
  short* g16   = (short*)(ws + (16ull<<20));     // [16,24)  fp16 G = mem_upd @ Wq
  short* m16   = (short*)(ws + (32ull<<20));     // [32,40)  fp16 mem (patched)
  short* wqT   = (short*)(ws + (40ull<<20));     // [40,42)  fp16 Wq^T [h][o]
  short* simP  = (short*)(ws + (48ull<<20));     // [48,112) fp16 logits, softmax in-place -> P
  short* vwoT  = (short*)(ws + (112ull<<20));    // [112,120) fp16 VWoT[o][m]
  short* wo16  = (short*)(ws + (132ull<<20));    // [132,134)
  char*  tail  = ws + (134ull<<20);
  float* biasM    = (float*)tail;
  float* surprise = (float*)(tail + (64<<10));
  float* top_vals = (float*)(tail + (128<<10));
  int*   top_idx  = (int*)  (tail + (129<<10));
  int*   slots    = (int*)  (tail + (130<<10));
  unsigned long long* cand_s = (unsigned long long*)(tail + (132<<10));  // 16 KB
  unsigned long long* cand_i = (unsigned long long*)(tail + (148<<10));  // 8 KB

  static bool attr_done = false;
  if (!attr_done){
    (void)hipFuncSetAttribute(reinterpret_cast<const void*>(&gemm256<1>),
                              hipFuncAttributeMaxDynamicSharedMemorySize, 131072);
    (void)hipFuncSetAttribute(reinterpret_cast<const void*>(&gemm_out),
                              hipFuncAttributeMaxDynamicSharedMemorySize, 98304);
    (void)hipFuncSetAttribute(reinterpret_cast<const void*>(&gemm_dual2),
                              hipFuncAttributeMaxDynamicSharedMemorySize, 98304);
    attr_done = true;
  }

  // LN (8192 blocks) + prep (5376 blocks) fused: independent work, 1 launch
  ln_prep_kernel<<<NTOK + 5376, 256, 0, stream>>>(
      hs, gam, bet, mem, Wq, Wo, bq, n16, surprise, m16, wqT, wo16, biasM);
  topk_local<<<48, 256, 0, stream>>>(surprise, imp, cand_s, cand_i);
  topk_merge<<<2, 256, 0, stream>>>(cand_s, cand_i, top_vals, top_idx, slots);
  update_kernel<<<KTOP, 256, 0, stream>>>(top_vals, top_idx, slots, hs, gam, bet, bq, m16, biasM);
  // VWoT[o][m] = Wo[o][:].mem_upd[m][:]  and  G[m][h] = mem_upd[m][:].wqT[h][:]
  // via the proven 8-phase body (256 blocks = 1 wg/CU)
  gemm_dual2<<<256, 512, 98304, stream>>>(
      wo16, m16, m16, wqT, vwoT, g16, H);
  // sim = norm @ G^T + biasM  -- 256x256 8-phase pipelined GEMM (8x8 XCD rect)
  gemm256<1><<<dim3(16,32), 512, 131072, stream>>>(
      n16, g16, H, MMEM, simP, nullptr, nullptr, biasM);
  // softmax rows in-place -> P fp16 (normalized)
  softmax_kernel<<<NTOK, 256, 0, stream>>>(simP);
  // out = hidden + P @ VWoT^T + bo   -- 128x256 8-phase pipelined GEMM
  gemm_out<<<dim3(4, 64), 512, 98304, stream>>>(
      simP, vwoT, MMEM, H, out, hs, bo);
}